// Round 7
// baseline (713.974 us; speedup 1.0000x reference)
//
#include <hip/hip_runtime.h>
#include <hip/hip_bf16.h>

using u16 = unsigned short;
using u32 = unsigned int;

#define BB 512
#define SS 100
#define LL 30
#define DD 400
#define MM 128
#define HH 20
#define DHH 20
#define SLAB 1024000ull   // 51200 * 20  (one head's q/k/v slab, elements)

typedef short v8s __attribute__((ext_vector_type(8)));   // 8 bf16 = 4 VGPR
typedef float v4f __attribute__((ext_vector_type(4)));   // MFMA 16x16 acc

__device__ __forceinline__ float lo2f(u32 u) { return __uint_as_float(u << 16); }
__device__ __forceinline__ float hi2f(u32 u) { return __uint_as_float(u & 0xffff0000u); }
__device__ __forceinline__ float bf2f(u16 h) { return __uint_as_float(((u32)h) << 16); }
__device__ __forceinline__ u16 f2bf(float f) {
  u32 u = __float_as_uint(f);
  u += 0x7fffu + ((u >> 16) & 1u);
  return (u16)(u >> 16);
}
__device__ __forceinline__ u32 packf2(float a, float b) {
  return (u32)f2bf(a) | (((u32)f2bf(b)) << 16);
}

// ---------------------------------------------------------------------------
// K0a: f32 -> bf16 bulk convert (emb table).  n4 = elements/4.
// ---------------------------------------------------------------------------
__global__ __launch_bounds__(256) void k_cvt(const float* __restrict__ src,
                                             u16* __restrict__ dst, int n4) {
  const int i = blockIdx.x * 256 + threadIdx.x;
  if (i < n4) {
    const float4 v = ((const float4*)src)[i];
    ((uint2*)dst)[i] = make_uint2(packf2(v.x, v.y), packf2(v.z, v.w));
  }
}

// ---------------------------------------------------------------------------
// K0b: transpose-convert  src f32 [K][N]  ->  dst bf16 [N][K].
// ---------------------------------------------------------------------------
__global__ __launch_bounds__(256) void k_trans(const float* __restrict__ src,
                                               u16* __restrict__ dst, int K, int N) {
  __shared__ float ts[32][33];
  const int t = threadIdx.x;
  const int n0 = blockIdx.x * 32, k0 = blockIdx.y * 32;
  const int c = t & 31, r8 = t >> 5;
#pragma unroll
  for (int i = 0; i < 4; ++i) {
    const int k = k0 + r8 + i * 8, n = n0 + c;
    ts[r8 + i * 8][c] = (k < K && n < N) ? src[(size_t)k * N + n] : 0.f;
  }
  __syncthreads();
#pragma unroll
  for (int i = 0; i < 4; ++i) {
    const int n = n0 + r8 + i * 8, k = k0 + c;
    if (n < N && k < K) dst[(size_t)n * K + k] = f2bf(ts[c][r8 + i * 8]);
  }
}

// ---------------------------------------------------------------------------
// K1: embedding gather + mean pool (bf16 table).  wave-per-(b,s) row.
// ---------------------------------------------------------------------------
__global__ __launch_bounds__(256) void k_embed(const int* __restrict__ uc,
                                               const u16* __restrict__ emb,
                                               u32* __restrict__ click) {
  const int wave = threadIdx.x >> 6, lane = threadIdx.x & 63;
  const int bs = blockIdx.x * 4 + wave;
  __shared__ int rows[4][LL];
  if (lane < LL) rows[wave][lane] = uc[(size_t)bs * LL + lane];
  __syncthreads();
  float ax[4] = {0.f, 0.f, 0.f, 0.f}, ay[4] = {0.f, 0.f, 0.f, 0.f};
  for (int l = 0; l < LL; ++l) {
    const u32* row = (const u32*)(emb + (size_t)rows[wave][l] * DD);
    const u32 a = row[lane], b = row[lane + 64], c = row[lane + 128];
    ax[0] += lo2f(a); ay[0] += hi2f(a);
    ax[1] += lo2f(b); ay[1] += hi2f(b);
    ax[2] += lo2f(c); ay[2] += hi2f(c);
    if (lane < 8) { const u32 d = row[lane + 192]; ax[3] += lo2f(d); ay[3] += hi2f(d); }
  }
  const float s = 1.0f / (float)LL;
  u32* orow = click + (size_t)bs * 200;
  orow[lane]       = packf2(ax[0] * s, ay[0] * s);
  orow[lane + 64]  = packf2(ax[1] * s, ay[1] * s);
  orow[lane + 128] = packf2(ax[2] * s, ay[2] * s);
  if (lane < 8) orow[lane + 192] = packf2(ax[3] * s, ay[3] * s);
}

// ---------------------------------------------------------------------------
// K2: QKV projection, bf16 MFMA.  grid (200, 5); block loops mat = q,k,v
// reusing its staged A-tile (L2-hot re-reads instead of 15x HBM refetch).
// Output HEAD-MAJOR: O[h][m][dh], h = col/20, dh = col%20.
// ---------------------------------------------------------------------------
__global__ __launch_bounds__(256) void k_qkv_mfma(const u16* __restrict__ A,
    const u16* __restrict__ Wt, u16* __restrict__ qo, u16* __restrict__ ko_,
    u16* __restrict__ vo) {
  __shared__ u16 As[256][40];
  __shared__ u16 Bs[80][40];
  const int t = threadIdx.x;
  const int wave = t >> 6, lane = t & 63;
  const int q = lane >> 4, l16 = lane & 15;
  const int m0 = blockIdx.x * 256;
  const int nb = blockIdx.y * 80;
  const int mw = wave * 64;

  for (int mat = 0; mat < 3; ++mat) {
    const u16* Bt = Wt + (size_t)(mat * 400 + nb) * 400;
    u16* O = (mat == 0) ? qo : ((mat == 1) ? ko_ : vo);
    v4f acc[4][5];
#pragma unroll
    for (int i = 0; i < 4; ++i)
#pragma unroll
      for (int j = 0; j < 5; ++j) acc[i][j] = (v4f){0.f, 0.f, 0.f, 0.f};

    for (int kt = 0; kt < 13; ++kt) {
      const int k0 = kt * 32;
#pragma unroll
      for (int i = 0; i < 4; ++i) {
        const int id = i * 256 + t;
        const int r = id >> 2, ko = (id & 3) * 8;
        uint4 val = make_uint4(0u, 0u, 0u, 0u);
        if (k0 + ko < 400) val = *(const uint4*)&A[(size_t)(m0 + r) * 400 + k0 + ko];
        *(uint4*)&As[r][ko] = val;
      }
#pragma unroll
      for (int i = 0; i < 2; ++i) {
        const int id = i * 256 + t;
        if (id < 320) {
          const int n = id >> 2, ko = (id & 3) * 8;
          uint4 val = make_uint4(0u, 0u, 0u, 0u);
          if (k0 + ko < 400) val = *(const uint4*)&Bt[(size_t)n * 400 + k0 + ko];
          *(uint4*)&Bs[n][ko] = val;
        }
      }
      __syncthreads();
      v8s a[4], b[5];
#pragma unroll
      for (int ms = 0; ms < 4; ++ms) a[ms] = *(const v8s*)&As[mw + ms * 16 + l16][q * 8];
#pragma unroll
      for (int ns = 0; ns < 5; ++ns) b[ns] = *(const v8s*)&Bs[ns * 16 + l16][q * 8];
#pragma unroll
      for (int ms = 0; ms < 4; ++ms)
#pragma unroll
        for (int ns = 0; ns < 5; ++ns)
          acc[ms][ns] = __builtin_amdgcn_mfma_f32_16x16x32_bf16(a[ms], b[ns], acc[ms][ns], 0, 0, 0);
      __syncthreads();
    }
    // epilogue: head-major store.  D layout col = l16, row = q*4 + reg
#pragma unroll
    for (int ms = 0; ms < 4; ++ms)
#pragma unroll
      for (int ns = 0; ns < 5; ++ns) {
        const v4f c = acc[ms][ns];
        const int col = nb + ns * 16 + l16;
        const int head = col / 20, dh = col % 20;
        u16* Oh = O + (size_t)head * SLAB + dh;
#pragma unroll
        for (int reg = 0; reg < 4; ++reg) {
          const int m = m0 + mw + ms * 16 + q * 4 + reg;
          Oh[(size_t)m * 20] = f2bf(c[reg]);
        }
      }
  }
}

// ---------------------------------------------------------------------------
// K3: MFMA attention, head-major q/k/v input (contiguous 4 KB per tensor
// per block).  One block per (b,h), 4 waves.  ctx written [bs][400].
// ---------------------------------------------------------------------------
__global__ __launch_bounds__(256) void k_attn_mfma(const u16* __restrict__ qg,
    const u16* __restrict__ kg, const u16* __restrict__ vg,
    const int* __restrict__ seq, u16* __restrict__ ctxg) {
  __shared__ u16 Qs[112][40];
  __shared__ u16 Ks[112][40];
  __shared__ u16 Vs[112][40];
  __shared__ u16 Vt[32][136];
  __shared__ u16 Ss[112][136];
  const int b = blockIdx.x / HH, h = blockIdx.x % HH;
  const int t = threadIdx.x;
  const int wave = t >> 6, lane = t & 63;
  const int quad = lane >> 4, l16 = lane & 15;
  const int len = seq[b];
  const u16* qb = qg + (size_t)h * SLAB + (size_t)b * SS * DHH;
  const u16* kb = kg + (size_t)h * SLAB + (size_t)b * SS * DHH;
  const u16* vb = vg + (size_t)h * SLAB + (size_t)b * SS * DHH;
  // stage Q,K,V: contiguous [100][20] slabs; rows>=100 / cols>=20 zero
  for (int id = t; id < 896; id += 256) {
    const int r = id >> 3, ch = id & 7;
    uint2 vq = make_uint2(0u, 0u), vk = vq, vv = vq;
    if (r < 100 && ch < 5) {
      vq = *(const uint2*)(qb + r * DHH + ch * 4);
      vk = *(const uint2*)(kb + r * DHH + ch * 4);
      vv = *(const uint2*)(vb + r * DHH + ch * 4);
    }
    *(uint2*)&Qs[r][ch * 4] = vq;
    *(uint2*)&Ks[r][ch * 4] = vk;
    *(uint2*)&Vs[r][ch * 4] = vv;
  }
  // zero pads: Vt rows 20-31; Vt cols 100-135; Ss cols 112-127
  for (int id = t; id < 816; id += 256) ((u32*)&Vt[20][0])[id] = 0u;
  for (int id = t; id < 360; id += 256) {
    const int r = id / 18, c = id % 18;
    *(u32*)&Vt[r][100 + c * 2] = 0u;
  }
  for (int id = t; id < 896; id += 256) {
    const int r = id >> 3, c = id & 7;
    *(u32*)&Ss[r][112 + c * 2] = 0u;
  }
  __syncthreads();
  // transpose Vs -> Vt (d<20, key<100)
  for (int id = t; id < 2000; id += 256) {
    const int d = id / 100, key = id % 100;
    Vt[d][key] = Vs[key][d];
  }
  // QK^T + row softmax
  const float sc = 0.2236067977499790f;  // 1/sqrt(20)
  for (int mi = 0; mi < 2; ++mi) {
    const int mt = wave + mi * 4;
    if (mt >= 7) break;
    const v8s a = *(const v8s*)&Qs[mt * 16 + l16][quad * 8];
    v4f acc[7];
#pragma unroll
    for (int nt = 0; nt < 7; ++nt) {
      const v8s bk = *(const v8s*)&Ks[nt * 16 + l16][quad * 8];
      acc[nt] = __builtin_amdgcn_mfma_f32_16x16x32_bf16(a, bk, (v4f){0.f,0.f,0.f,0.f}, 0, 0, 0);
    }
#pragma unroll
    for (int reg = 0; reg < 4; ++reg) {
      float v[7];
      float mx = -3.0e38f;
#pragma unroll
      for (int nt = 0; nt < 7; ++nt) {
        const int col = nt * 16 + l16;
        v[nt] = acc[nt][reg] * sc + ((col < len) ? 1.0f : -1e9f);
        mx = fmaxf(mx, v[nt]);
      }
#pragma unroll
      for (int o = 1; o < 16; o <<= 1) mx = fmaxf(mx, __shfl_xor(mx, o));
      float sum = 0.f;
#pragma unroll
      for (int nt = 0; nt < 7; ++nt) { v[nt] = __expf(v[nt] - mx); sum += v[nt]; }
#pragma unroll
      for (int o = 1; o < 16; o <<= 1) sum += __shfl_xor(sum, o);
      const float inv = 1.0f / sum;
      const int row = mt * 16 + quad * 4 + reg;
#pragma unroll
      for (int nt = 0; nt < 7; ++nt) Ss[row][nt * 16 + l16] = f2bf(v[nt] * inv);
    }
  }
  __syncthreads();
  // PV: ctx[q][d] = sum_k P[q][k] V[k][d]
  u16* cb = ctxg + (size_t)b * SS * DD + h * DHH;
  for (int mi = 0; mi < 2; ++mi) {
    const int mt = wave + mi * 4;
    if (mt >= 7) break;
    v4f o0 = (v4f){0.f,0.f,0.f,0.f}, o1 = o0;
#pragma unroll
    for (int kc = 0; kc < 4; ++kc) {
      const v8s a  = *(const v8s*)&Ss[mt * 16 + l16][kc * 32 + quad * 8];
      const v8s b0 = *(const v8s*)&Vt[l16][kc * 32 + quad * 8];
      const v8s b1 = *(const v8s*)&Vt[16 + l16][kc * 32 + quad * 8];
      o0 = __builtin_amdgcn_mfma_f32_16x16x32_bf16(a, b0, o0, 0, 0, 0);
      o1 = __builtin_amdgcn_mfma_f32_16x16x32_bf16(a, b1, o1, 0, 0, 0);
    }
#pragma unroll
    for (int reg = 0; reg < 4; ++reg) {
      const int q = mt * 16 + quad * 4 + reg;
      if (q < 100) {
        cb[(size_t)q * DD + l16] = f2bf(o0[reg]);
        if (l16 < 4) cb[(size_t)q * DD + 16 + l16] = f2bf(o1[reg]);
      }
    }
  }
}

// ---------------------------------------------------------------------------
// K4: e = tanh(ctx @ fc1_w + fc1_b), bf16 MFMA (unchanged — verified).
// ---------------------------------------------------------------------------
__global__ __launch_bounds__(256) void k_fc1_mfma(const u16* __restrict__ A,
    const u16* __restrict__ Bt, const float* __restrict__ f1b,
    float* __restrict__ e) {
  __shared__ u16 As[128][40];
  __shared__ u16 Bs[64][40];
  const int t = threadIdx.x;
  const int wave = t >> 6, lane = t & 63;
  const int q = lane >> 4, l16 = lane & 15;
  const int m0 = blockIdx.x * 128;
  const int nb = blockIdx.y * 64;
  const int mw = wave * 32;
  v4f acc[2][4];
#pragma unroll
  for (int i = 0; i < 2; ++i)
#pragma unroll
    for (int j = 0; j < 4; ++j) acc[i][j] = (v4f){0.f, 0.f, 0.f, 0.f};

  for (int kt = 0; kt < 13; ++kt) {
    const int k0 = kt * 32;
#pragma unroll
    for (int i = 0; i < 2; ++i) {
      const int id = i * 256 + t;
      const int r = id >> 2, ko = (id & 3) * 8;
      uint4 val = make_uint4(0u, 0u, 0u, 0u);
      if (k0 + ko < 400) val = *(const uint4*)&A[(size_t)(m0 + r) * 400 + k0 + ko];
      *(uint4*)&As[r][ko] = val;
    }
    {
      const int r = t >> 2, ko = (t & 3) * 8;
      uint4 val = make_uint4(0u, 0u, 0u, 0u);
      if (k0 + ko < 400) val = *(const uint4*)&Bt[(size_t)(nb + r) * 400 + k0 + ko];
      *(uint4*)&Bs[r][ko] = val;
    }
    __syncthreads();
    v8s a[2], b[4];
#pragma unroll
    for (int ms = 0; ms < 2; ++ms) a[ms] = *(const v8s*)&As[mw + ms * 16 + l16][q * 8];
#pragma unroll
    for (int ns = 0; ns < 4; ++ns) b[ns] = *(const v8s*)&Bs[ns * 16 + l16][q * 8];
#pragma unroll
    for (int ms = 0; ms < 2; ++ms)
#pragma unroll
      for (int ns = 0; ns < 4; ++ns)
        acc[ms][ns] = __builtin_amdgcn_mfma_f32_16x16x32_bf16(a[ms], b[ns], acc[ms][ns], 0, 0, 0);
    __syncthreads();
  }
#pragma unroll
  for (int ms = 0; ms < 2; ++ms)
#pragma unroll
    for (int ns = 0; ns < 4; ++ns) {
      const v4f c = acc[ms][ns];
      const int col = nb + ns * 16 + l16;
      const float bias = f1b[col];
#pragma unroll
      for (int reg = 0; reg < 4; ++reg) {
        const int m = m0 + mw + ms * 16 + q * 4 + reg;
        e[(size_t)m * MM + col] = tanhf(c[reg] + bias);
      }
    }
}

// ---------------------------------------------------------------------------
// K5: additive attention pooling (unchanged — verified).
// ---------------------------------------------------------------------------
__global__ __launch_bounds__(256) void k_pool(const float* __restrict__ e,
    const float* __restrict__ f2w, const float* __restrict__ f2b,
    const int* __restrict__ seq, const u16* __restrict__ ctxg,
    float* __restrict__ out) {
  const int b = blockIdx.x;
  const int t = threadIdx.x, w = t >> 6, lane = t & 63;
  __shared__ float wts[SS];
  __shared__ float fw[MM];
  if (t < MM) fw[t] = f2w[t];
  __syncthreads();
  const int len = seq[b];
  const float bias = f2b[0];
  for (int s = w; s < SS; s += 4) {
    const float* er = e + (size_t)(b * SS + s) * MM;
    float p = er[lane] * fw[lane] + er[lane + 64] * fw[lane + 64];
#pragma unroll
    for (int o = 32; o > 0; o >>= 1) p += __shfl_down(p, o);
    if (lane == 0) wts[s] = p + bias + ((s < len) ? 1.0f : -1e9f);
  }
  __syncthreads();
  if (w == 0) {
    const float v0 = wts[lane];
    const float v1 = (lane + 64 < SS) ? wts[lane + 64] : -3.0e38f;
    float mx = fmaxf(v0, v1);
#pragma unroll
    for (int o = 32; o > 0; o >>= 1) mx = fmaxf(mx, __shfl_xor(mx, o));
    const float e0 = __expf(v0 - mx);
    const float e1 = (lane + 64 < SS) ? __expf(v1 - mx) : 0.f;
    float sm = e0 + e1;
#pragma unroll
    for (int o = 32; o > 0; o >>= 1) sm += __shfl_xor(sm, o);
    const float inv = 1.0f / sm;
    wts[lane] = e0 * inv;
    if (lane + 64 < SS) wts[lane + 64] = e1 * inv;
  }
  __syncthreads();
  for (int d = t; d < DD; d += 256) {
    float acc = 0.f;
    const u16* cb = ctxg + (size_t)b * SS * DD + d;
    for (int s = 0; s < SS; ++s) acc += wts[s] * bf2f(cb[(size_t)s * DD]);
    out[(size_t)b * DD + d] = acc;
  }
}

// ---------------------------------------------------------------------------
extern "C" void kernel_launch(void* const* d_in, const int* in_sizes, int n_in,
                              void* d_out, int out_size, void* d_ws, size_t ws_size,
                              hipStream_t stream) {
  const int*   uc  = (const int*)d_in[0];
  const int*   seq = (const int*)d_in[1];
  const float* emb = (const float*)d_in[2];
  const float* wq  = (const float*)d_in[3];
  const float* wk  = (const float*)d_in[4];
  const float* wv  = (const float*)d_in[5];
  const float* f1w = (const float*)d_in[6];
  const float* f1b = (const float*)d_in[7];
  const float* f2w = (const float*)d_in[8];
  const float* f2b = (const float*)d_in[9];
  float* out = (float*)d_out;

  u16* emb16   = (u16*)d_ws;
  u16* wt      = emb16 + 20000000ull;
  u16* wtf     = wt + 480000ull;
  u16* click16 = wtf + 51200ull;               // also ctx16 ([bs][400])
  u16* q16     = click16 + 20480000ull;        // head-major [20][51200][20]
  u16* k16     = q16 + 20480000ull;
  u16* v16     = k16 + 20480000ull;
  float* e     = (float*)q16;                  // q dead after attn

  k_cvt<<<(5000000 + 255) / 256, 256, 0, stream>>>(emb, emb16, 5000000);
  k_trans<<<dim3(13, 13), 256, 0, stream>>>(wq, wt, 400, 400);
  k_trans<<<dim3(13, 13), 256, 0, stream>>>(wk, wt + 160000, 400, 400);
  k_trans<<<dim3(13, 13), 256, 0, stream>>>(wv, wt + 320000, 400, 400);
  k_trans<<<dim3(4, 13), 256, 0, stream>>>(f1w, wtf, 400, 128);
  k_embed<<<12800, 256, 0, stream>>>(uc, emb16, (u32*)click16);
  k_qkv_mfma<<<dim3(200, 5), 256, 0, stream>>>(click16, wt, q16, k16, v16);
  k_attn_mfma<<<BB * HH, 256, 0, stream>>>(q16, k16, v16, seq, click16);
  k_fc1_mfma<<<dim3(400, 2), 256, 0, stream>>>(click16, wtf, f1b, e);
  k_pool<<<BB, 256, 0, stream>>>(e, f2w, f2b, seq, click16, out);
}

// Round 8
// 660.353 us; speedup vs baseline: 1.0812x; 1.0812x over previous
//
#include <hip/hip_runtime.h>
#include <hip/hip_bf16.h>

using u16 = unsigned short;
using u32 = unsigned int;

#define BB 512
#define SS 100
#define LL 30
#define DD 400
#define MM 128
#define HH 20
#define DHH 20
#define SLAB 1024000ull   // 51200 * 20  (one head's q/k/v slab, elements)

typedef short v8s __attribute__((ext_vector_type(8)));   // 8 bf16 = 4 VGPR
typedef float v4f __attribute__((ext_vector_type(4)));   // MFMA 16x16 acc

__device__ __forceinline__ float lo2f(u32 u) { return __uint_as_float(u << 16); }
__device__ __forceinline__ float hi2f(u32 u) { return __uint_as_float(u & 0xffff0000u); }
__device__ __forceinline__ float bf2f(u16 h) { return __uint_as_float(((u32)h) << 16); }
__device__ __forceinline__ u16 f2bf(float f) {
  u32 u = __float_as_uint(f);
  u += 0x7fffu + ((u >> 16) & 1u);
  return (u16)(u >> 16);
}
__device__ __forceinline__ u32 packf2(float a, float b) {
  return (u32)f2bf(a) | (((u32)f2bf(b)) << 16);
}

// ---------------------------------------------------------------------------
// K0a: f32 -> bf16 bulk convert (emb table).  n4 = elements/4.
// ---------------------------------------------------------------------------
__global__ __launch_bounds__(256) void k_cvt(const float* __restrict__ src,
                                             u16* __restrict__ dst, int n4) {
  const int i = blockIdx.x * 256 + threadIdx.x;
  if (i < n4) {
    const float4 v = ((const float4*)src)[i];
    ((uint2*)dst)[i] = make_uint2(packf2(v.x, v.y), packf2(v.z, v.w));
  }
}

// ---------------------------------------------------------------------------
// K0b: transpose-convert  src f32 [K][N]  ->  dst bf16 [N][K].
// ---------------------------------------------------------------------------
__global__ __launch_bounds__(256) void k_trans(const float* __restrict__ src,
                                               u16* __restrict__ dst, int K, int N) {
  __shared__ float ts[32][33];
  const int t = threadIdx.x;
  const int n0 = blockIdx.x * 32, k0 = blockIdx.y * 32;
  const int c = t & 31, r8 = t >> 5;
#pragma unroll
  for (int i = 0; i < 4; ++i) {
    const int k = k0 + r8 + i * 8, n = n0 + c;
    ts[r8 + i * 8][c] = (k < K && n < N) ? src[(size_t)k * N + n] : 0.f;
  }
  __syncthreads();
#pragma unroll
  for (int i = 0; i < 4; ++i) {
    const int n = n0 + r8 + i * 8, k = k0 + c;
    if (n < N && k < K) dst[(size_t)n * K + k] = f2bf(ts[c][r8 + i * 8]);
  }
}

// ---------------------------------------------------------------------------
// K1: embedding gather + mean pool (bf16 table).  wave-per-(b,s) row.
// ---------------------------------------------------------------------------
__global__ __launch_bounds__(256) void k_embed(const int* __restrict__ uc,
                                               const u16* __restrict__ emb,
                                               u32* __restrict__ click) {
  const int wave = threadIdx.x >> 6, lane = threadIdx.x & 63;
  const int bs = blockIdx.x * 4 + wave;
  __shared__ int rows[4][LL];
  if (lane < LL) rows[wave][lane] = uc[(size_t)bs * LL + lane];
  __syncthreads();
  float ax[4] = {0.f, 0.f, 0.f, 0.f}, ay[4] = {0.f, 0.f, 0.f, 0.f};
  for (int l = 0; l < LL; ++l) {
    const u32* row = (const u32*)(emb + (size_t)rows[wave][l] * DD);
    const u32 a = row[lane], b = row[lane + 64], c = row[lane + 128];
    ax[0] += lo2f(a); ay[0] += hi2f(a);
    ax[1] += lo2f(b); ay[1] += hi2f(b);
    ax[2] += lo2f(c); ay[2] += hi2f(c);
    if (lane < 8) { const u32 d = row[lane + 192]; ax[3] += lo2f(d); ay[3] += hi2f(d); }
  }
  const float s = 1.0f / (float)LL;
  u32* orow = click + (size_t)bs * 200;
  orow[lane]       = packf2(ax[0] * s, ay[0] * s);
  orow[lane + 64]  = packf2(ax[1] * s, ay[1] * s);
  orow[lane + 128] = packf2(ax[2] * s, ay[2] * s);
  if (lane < 8) orow[lane + 192] = packf2(ax[3] * s, ay[3] * s);
}

// ---------------------------------------------------------------------------
// K2: QKV projection, bf16 MFMA.  R6 structure: grid (200, 15), one mat per
// block (mat = y/5, ntile = y%5) — A refetches served by L3 (41 MB << 256 MB).
// HEAD-MAJOR output: O[h][m][dh], h = col/20, dh = col%20 (for attn locality).
// ---------------------------------------------------------------------------
__global__ __launch_bounds__(256) void k_qkv_mfma(const u16* __restrict__ A,
    const u16* __restrict__ Wt, u16* __restrict__ qo, u16* __restrict__ ko_,
    u16* __restrict__ vo) {
  __shared__ u16 As[256][40];
  __shared__ u16 Bs[80][40];
  const int t = threadIdx.x;
  const int wave = t >> 6, lane = t & 63;
  const int q = lane >> 4, l16 = lane & 15;
  const int m0 = blockIdx.x * 256;
  const int mat = blockIdx.y / 5, ntile = blockIdx.y % 5;
  const int nb = ntile * 80;
  const u16* Bt = Wt + (size_t)(mat * 400 + nb) * 400;
  u16* O = (mat == 0) ? qo : ((mat == 1) ? ko_ : vo);
  const int mw = wave * 64;

  v4f acc[4][5];
#pragma unroll
  for (int i = 0; i < 4; ++i)
#pragma unroll
    for (int j = 0; j < 5; ++j) acc[i][j] = (v4f){0.f, 0.f, 0.f, 0.f};

  for (int kt = 0; kt < 13; ++kt) {
    const int k0 = kt * 32;
#pragma unroll
    for (int i = 0; i < 4; ++i) {
      const int id = i * 256 + t;
      const int r = id >> 2, ko = (id & 3) * 8;
      uint4 val = make_uint4(0u, 0u, 0u, 0u);
      if (k0 + ko < 400) val = *(const uint4*)&A[(size_t)(m0 + r) * 400 + k0 + ko];
      *(uint4*)&As[r][ko] = val;
    }
#pragma unroll
    for (int i = 0; i < 2; ++i) {
      const int id = i * 256 + t;
      if (id < 320) {
        const int n = id >> 2, ko = (id & 3) * 8;
        uint4 val = make_uint4(0u, 0u, 0u, 0u);
        if (k0 + ko < 400) val = *(const uint4*)&Bt[(size_t)n * 400 + k0 + ko];
        *(uint4*)&Bs[n][ko] = val;
      }
    }
    __syncthreads();
    v8s a[4], b[5];
#pragma unroll
    for (int ms = 0; ms < 4; ++ms) a[ms] = *(const v8s*)&As[mw + ms * 16 + l16][q * 8];
#pragma unroll
    for (int ns = 0; ns < 5; ++ns) b[ns] = *(const v8s*)&Bs[ns * 16 + l16][q * 8];
#pragma unroll
    for (int ms = 0; ms < 4; ++ms)
#pragma unroll
      for (int ns = 0; ns < 5; ++ns)
        acc[ms][ns] = __builtin_amdgcn_mfma_f32_16x16x32_bf16(a[ms], b[ns], acc[ms][ns], 0, 0, 0);
    __syncthreads();
  }
  // epilogue: head-major store.  D layout col = l16, row = q*4 + reg
#pragma unroll
  for (int ms = 0; ms < 4; ++ms)
#pragma unroll
    for (int ns = 0; ns < 5; ++ns) {
      const v4f c = acc[ms][ns];
      const int col = nb + ns * 16 + l16;
      const int head = col / 20, dh = col % 20;
      u16* Oh = O + (size_t)head * SLAB + dh;
#pragma unroll
      for (int reg = 0; reg < 4; ++reg) {
        const int m = m0 + mw + ms * 16 + q * 4 + reg;
        Oh[(size_t)m * 20] = f2bf(c[reg]);
      }
    }
}

// ---------------------------------------------------------------------------
// K3: MFMA attention, head-major q/k/v input (contiguous 4 KB per tensor
// per block).  One block per (b,h), 4 waves.  ctx written [bs][400].
// ---------------------------------------------------------------------------
__global__ __launch_bounds__(256) void k_attn_mfma(const u16* __restrict__ qg,
    const u16* __restrict__ kg, const u16* __restrict__ vg,
    const int* __restrict__ seq, u16* __restrict__ ctxg) {
  __shared__ u16 Qs[112][40];
  __shared__ u16 Ks[112][40];
  __shared__ u16 Vs[112][40];
  __shared__ u16 Vt[32][136];
  __shared__ u16 Ss[112][136];
  const int b = blockIdx.x / HH, h = blockIdx.x % HH;
  const int t = threadIdx.x;
  const int wave = t >> 6, lane = t & 63;
  const int quad = lane >> 4, l16 = lane & 15;
  const int len = seq[b];
  const u16* qb = qg + (size_t)h * SLAB + (size_t)b * SS * DHH;
  const u16* kb = kg + (size_t)h * SLAB + (size_t)b * SS * DHH;
  const u16* vb = vg + (size_t)h * SLAB + (size_t)b * SS * DHH;
  // stage Q,K,V: contiguous [100][20] slabs; rows>=100 / cols>=20 zero
  for (int id = t; id < 896; id += 256) {
    const int r = id >> 3, ch = id & 7;
    uint2 vq = make_uint2(0u, 0u), vk = vq, vv = vq;
    if (r < 100 && ch < 5) {
      vq = *(const uint2*)(qb + r * DHH + ch * 4);
      vk = *(const uint2*)(kb + r * DHH + ch * 4);
      vv = *(const uint2*)(vb + r * DHH + ch * 4);
    }
    *(uint2*)&Qs[r][ch * 4] = vq;
    *(uint2*)&Ks[r][ch * 4] = vk;
    *(uint2*)&Vs[r][ch * 4] = vv;
  }
  // zero pads: Vt rows 20-31; Vt cols 100-135; Ss cols 112-127
  for (int id = t; id < 816; id += 256) ((u32*)&Vt[20][0])[id] = 0u;
  for (int id = t; id < 360; id += 256) {
    const int r = id / 18, c = id % 18;
    *(u32*)&Vt[r][100 + c * 2] = 0u;
  }
  for (int id = t; id < 896; id += 256) {
    const int r = id >> 3, c = id & 7;
    *(u32*)&Ss[r][112 + c * 2] = 0u;
  }
  __syncthreads();
  // transpose Vs -> Vt (d<20, key<100)
  for (int id = t; id < 2000; id += 256) {
    const int d = id / 100, key = id % 100;
    Vt[d][key] = Vs[key][d];
  }
  // QK^T + row softmax
  const float sc = 0.2236067977499790f;  // 1/sqrt(20)
  for (int mi = 0; mi < 2; ++mi) {
    const int mt = wave + mi * 4;
    if (mt >= 7) break;
    const v8s a = *(const v8s*)&Qs[mt * 16 + l16][quad * 8];
    v4f acc[7];
#pragma unroll
    for (int nt = 0; nt < 7; ++nt) {
      const v8s bk = *(const v8s*)&Ks[nt * 16 + l16][quad * 8];
      acc[nt] = __builtin_amdgcn_mfma_f32_16x16x32_bf16(a, bk, (v4f){0.f,0.f,0.f,0.f}, 0, 0, 0);
    }
#pragma unroll
    for (int reg = 0; reg < 4; ++reg) {
      float v[7];
      float mx = -3.0e38f;
#pragma unroll
      for (int nt = 0; nt < 7; ++nt) {
        const int col = nt * 16 + l16;
        v[nt] = acc[nt][reg] * sc + ((col < len) ? 1.0f : -1e9f);
        mx = fmaxf(mx, v[nt]);
      }
#pragma unroll
      for (int o = 1; o < 16; o <<= 1) mx = fmaxf(mx, __shfl_xor(mx, o));
      float sum = 0.f;
#pragma unroll
      for (int nt = 0; nt < 7; ++nt) { v[nt] = __expf(v[nt] - mx); sum += v[nt]; }
#pragma unroll
      for (int o = 1; o < 16; o <<= 1) sum += __shfl_xor(sum, o);
      const float inv = 1.0f / sum;
      const int row = mt * 16 + quad * 4 + reg;
#pragma unroll
      for (int nt = 0; nt < 7; ++nt) Ss[row][nt * 16 + l16] = f2bf(v[nt] * inv);
    }
  }
  __syncthreads();
  // PV: ctx[q][d] = sum_k P[q][k] V[k][d]
  u16* cb = ctxg + (size_t)b * SS * DD + h * DHH;
  for (int mi = 0; mi < 2; ++mi) {
    const int mt = wave + mi * 4;
    if (mt >= 7) break;
    v4f o0 = (v4f){0.f,0.f,0.f,0.f}, o1 = o0;
#pragma unroll
    for (int kc = 0; kc < 4; ++kc) {
      const v8s a  = *(const v8s*)&Ss[mt * 16 + l16][kc * 32 + quad * 8];
      const v8s b0 = *(const v8s*)&Vt[l16][kc * 32 + quad * 8];
      const v8s b1 = *(const v8s*)&Vt[16 + l16][kc * 32 + quad * 8];
      o0 = __builtin_amdgcn_mfma_f32_16x16x32_bf16(a, b0, o0, 0, 0, 0);
      o1 = __builtin_amdgcn_mfma_f32_16x16x32_bf16(a, b1, o1, 0, 0, 0);
    }
#pragma unroll
    for (int reg = 0; reg < 4; ++reg) {
      const int q = mt * 16 + quad * 4 + reg;
      if (q < 100) {
        cb[(size_t)q * DD + l16] = f2bf(o0[reg]);
        if (l16 < 4) cb[(size_t)q * DD + 16 + l16] = f2bf(o1[reg]);
      }
    }
  }
}

// ---------------------------------------------------------------------------
// K4: e = tanh(ctx @ fc1_w + fc1_b), bf16 MFMA (unchanged — verified).
// ---------------------------------------------------------------------------
__global__ __launch_bounds__(256) void k_fc1_mfma(const u16* __restrict__ A,
    const u16* __restrict__ Bt, const float* __restrict__ f1b,
    float* __restrict__ e) {
  __shared__ u16 As[128][40];
  __shared__ u16 Bs[64][40];
  const int t = threadIdx.x;
  const int wave = t >> 6, lane = t & 63;
  const int q = lane >> 4, l16 = lane & 15;
  const int m0 = blockIdx.x * 128;
  const int nb = blockIdx.y * 64;
  const int mw = wave * 32;
  v4f acc[2][4];
#pragma unroll
  for (int i = 0; i < 2; ++i)
#pragma unroll
    for (int j = 0; j < 4; ++j) acc[i][j] = (v4f){0.f, 0.f, 0.f, 0.f};

  for (int kt = 0; kt < 13; ++kt) {
    const int k0 = kt * 32;
#pragma unroll
    for (int i = 0; i < 2; ++i) {
      const int id = i * 256 + t;
      const int r = id >> 2, ko = (id & 3) * 8;
      uint4 val = make_uint4(0u, 0u, 0u, 0u);
      if (k0 + ko < 400) val = *(const uint4*)&A[(size_t)(m0 + r) * 400 + k0 + ko];
      *(uint4*)&As[r][ko] = val;
    }
    {
      const int r = t >> 2, ko = (t & 3) * 8;
      uint4 val = make_uint4(0u, 0u, 0u, 0u);
      if (k0 + ko < 400) val = *(const uint4*)&Bt[(size_t)(nb + r) * 400 + k0 + ko];
      *(uint4*)&Bs[r][ko] = val;
    }
    __syncthreads();
    v8s a[2], b[4];
#pragma unroll
    for (int ms = 0; ms < 2; ++ms) a[ms] = *(const v8s*)&As[mw + ms * 16 + l16][q * 8];
#pragma unroll
    for (int ns = 0; ns < 4; ++ns) b[ns] = *(const v8s*)&Bs[ns * 16 + l16][q * 8];
#pragma unroll
    for (int ms = 0; ms < 2; ++ms)
#pragma unroll
      for (int ns = 0; ns < 4; ++ns)
        acc[ms][ns] = __builtin_amdgcn_mfma_f32_16x16x32_bf16(a[ms], b[ns], acc[ms][ns], 0, 0, 0);
    __syncthreads();
  }
#pragma unroll
  for (int ms = 0; ms < 2; ++ms)
#pragma unroll
    for (int ns = 0; ns < 4; ++ns) {
      const v4f c = acc[ms][ns];
      const int col = nb + ns * 16 + l16;
      const float bias = f1b[col];
#pragma unroll
      for (int reg = 0; reg < 4; ++reg) {
        const int m = m0 + mw + ms * 16 + q * 4 + reg;
        e[(size_t)m * MM + col] = tanhf(c[reg] + bias);
      }
    }
}

// ---------------------------------------------------------------------------
// K5: additive attention pooling (unchanged — verified).
// ---------------------------------------------------------------------------
__global__ __launch_bounds__(256) void k_pool(const float* __restrict__ e,
    const float* __restrict__ f2w, const float* __restrict__ f2b,
    const int* __restrict__ seq, const u16* __restrict__ ctxg,
    float* __restrict__ out) {
  const int b = blockIdx.x;
  const int t = threadIdx.x, w = t >> 6, lane = t & 63;
  __shared__ float wts[SS];
  __shared__ float fw[MM];
  if (t < MM) fw[t] = f2w[t];
  __syncthreads();
  const int len = seq[b];
  const float bias = f2b[0];
  for (int s = w; s < SS; s += 4) {
    const float* er = e + (size_t)(b * SS + s) * MM;
    float p = er[lane] * fw[lane] + er[lane + 64] * fw[lane + 64];
#pragma unroll
    for (int o = 32; o > 0; o >>= 1) p += __shfl_down(p, o);
    if (lane == 0) wts[s] = p + bias + ((s < len) ? 1.0f : -1e9f);
  }
  __syncthreads();
  if (w == 0) {
    const float v0 = wts[lane];
    const float v1 = (lane + 64 < SS) ? wts[lane + 64] : -3.0e38f;
    float mx = fmaxf(v0, v1);
#pragma unroll
    for (int o = 32; o > 0; o >>= 1) mx = fmaxf(mx, __shfl_xor(mx, o));
    const float e0 = __expf(v0 - mx);
    const float e1 = (lane + 64 < SS) ? __expf(v1 - mx) : 0.f;
    float sm = e0 + e1;
#pragma unroll
    for (int o = 32; o > 0; o >>= 1) sm += __shfl_xor(sm, o);
    const float inv = 1.0f / sm;
    wts[lane] = e0 * inv;
    if (lane + 64 < SS) wts[lane + 64] = e1 * inv;
  }
  __syncthreads();
  for (int d = t; d < DD; d += 256) {
    float acc = 0.f;
    const u16* cb = ctxg + (size_t)b * SS * DD + d;
    for (int s = 0; s < SS; ++s) acc += wts[s] * bf2f(cb[(size_t)s * DD]);
    out[(size_t)b * DD + d] = acc;
  }
}

// ---------------------------------------------------------------------------
extern "C" void kernel_launch(void* const* d_in, const int* in_sizes, int n_in,
                              void* d_out, int out_size, void* d_ws, size_t ws_size,
                              hipStream_t stream) {
  const int*   uc  = (const int*)d_in[0];
  const int*   seq = (const int*)d_in[1];
  const float* emb = (const float*)d_in[2];
  const float* wq  = (const float*)d_in[3];
  const float* wk  = (const float*)d_in[4];
  const float* wv  = (const float*)d_in[5];
  const float* f1w = (const float*)d_in[6];
  const float* f1b = (const float*)d_in[7];
  const float* f2w = (const float*)d_in[8];
  const float* f2b = (const float*)d_in[9];
  float* out = (float*)d_out;

  u16* emb16   = (u16*)d_ws;
  u16* wt      = emb16 + 20000000ull;
  u16* wtf     = wt + 480000ull;
  u16* click16 = wtf + 51200ull;               // also ctx16 ([bs][400])
  u16* q16     = click16 + 20480000ull;        // head-major [20][51200][20]
  u16* k16     = q16 + 20480000ull;
  u16* v16     = k16 + 20480000ull;
  float* e     = (float*)q16;                  // q dead after attn

  k_cvt<<<(5000000 + 255) / 256, 256, 0, stream>>>(emb, emb16, 5000000);
  k_trans<<<dim3(13, 13), 256, 0, stream>>>(wq, wt, 400, 400);
  k_trans<<<dim3(13, 13), 256, 0, stream>>>(wk, wt + 160000, 400, 400);
  k_trans<<<dim3(13, 13), 256, 0, stream>>>(wv, wt + 320000, 400, 400);
  k_trans<<<dim3(4, 13), 256, 0, stream>>>(f1w, wtf, 400, 128);
  k_embed<<<12800, 256, 0, stream>>>(uc, emb16, (u32*)click16);
  k_qkv_mfma<<<dim3(200, 15), 256, 0, stream>>>(click16, wt, q16, k16, v16);
  k_attn_mfma<<<BB * HH, 256, 0, stream>>>(q16, k16, v16, seq, click16);
  k_fc1_mfma<<<dim3(400, 2), 256, 0, stream>>>(click16, wtf, f1b, e);
  k_pool<<<BB, 256, 0, stream>>>(e, f2w, f2b, seq, click16, out);
}

// Round 9
// 642.442 us; speedup vs baseline: 1.1113x; 1.0279x over previous
//
#include <hip/hip_runtime.h>
#include <hip/hip_bf16.h>

using u16 = unsigned short;
using u32 = unsigned int;

#define BB 512
#define SS 100
#define LL 30
#define DD 400
#define MM 128
#define HH 20
#define DHH 20
#define SLAB 1024000ull   // 51200 * 20  (one head's q/k/v slab, elements)

typedef short v8s __attribute__((ext_vector_type(8)));   // 8 bf16 = 4 VGPR
typedef float v4f __attribute__((ext_vector_type(4)));   // MFMA 16x16 acc

__device__ __forceinline__ float lo2f(u32 u) { return __uint_as_float(u << 16); }
__device__ __forceinline__ float hi2f(u32 u) { return __uint_as_float(u & 0xffff0000u); }
__device__ __forceinline__ float bf2f(u16 h) { return __uint_as_float(((u32)h) << 16); }
__device__ __forceinline__ u16 f2bf(float f) {
  u32 u = __float_as_uint(f);
  u += 0x7fffu + ((u >> 16) & 1u);
  return (u16)(u >> 16);
}
__device__ __forceinline__ u32 packf2(float a, float b) {
  return (u32)f2bf(a) | (((u32)f2bf(b)) << 16);
}

// ---------------------------------------------------------------------------
// K0a: f32 -> bf16 bulk convert (emb table).  n4 = elements/4.
// ---------------------------------------------------------------------------
__global__ __launch_bounds__(256) void k_cvt(const float* __restrict__ src,
                                             u16* __restrict__ dst, int n4) {
  const int i = blockIdx.x * 256 + threadIdx.x;
  if (i < n4) {
    const float4 v = ((const float4*)src)[i];
    ((uint2*)dst)[i] = make_uint2(packf2(v.x, v.y), packf2(v.z, v.w));
  }
}

// ---------------------------------------------------------------------------
// K0w: L3 warm pass over emb16 (sequential read -> Infinity Cache residency
// for k_embed's random gather) + zero the alpha accumulator.
// Data-dependent conditional write keeps the loads alive.
// ---------------------------------------------------------------------------
__global__ __launch_bounds__(256) void k_warm(const uint4* __restrict__ emb16,
                                              int n16, float* __restrict__ alpha,
                                              int nA, float* __restrict__ sink) {
  const int gid = blockIdx.x * 256 + threadIdx.x;
  const int stride = gridDim.x * 256;
  for (int i = gid; i < nA; i += stride) alpha[i] = 0.f;
  u32 s = 0;
  for (int i = gid; i < n16; i += stride) {
    const uint4 v = emb16[i];
    s += v.x ^ v.y ^ v.z ^ v.w;
  }
  if (s == 0x12345678u) sink[0] = 1.f;   // never true in practice
}

// ---------------------------------------------------------------------------
// K0b: transpose-convert, all four weight matrices in one launch.
// z in {0,1,2}: wq/wk/wv f32[400][400] -> wt + z*160000 (bf16 [400][400]^T)
// z == 3:      f1w f32[400][128] -> wtf (bf16 [128][400])
// ---------------------------------------------------------------------------
__global__ __launch_bounds__(256) void k_trans_all(const float* __restrict__ wq,
    const float* __restrict__ wk, const float* __restrict__ wv,
    const float* __restrict__ f1w, u16* __restrict__ wt, u16* __restrict__ wtf) {
  __shared__ float ts[32][33];
  const int z = blockIdx.z;
  const float* src = (z == 0) ? wq : (z == 1) ? wk : (z == 2) ? wv : f1w;
  u16* dst = (z < 3) ? (wt + (size_t)z * 160000) : wtf;
  const int N = (z < 3) ? 400 : 128;
  const int K = 400;
  const int t = threadIdx.x;
  const int n0 = blockIdx.x * 32, k0 = blockIdx.y * 32;
  const int c = t & 31, r8 = t >> 5;
#pragma unroll
  for (int i = 0; i < 4; ++i) {
    const int k = k0 + r8 + i * 8, n = n0 + c;
    ts[r8 + i * 8][c] = (k < K && n < N) ? src[(size_t)k * N + n] : 0.f;
  }
  __syncthreads();
#pragma unroll
  for (int i = 0; i < 4; ++i) {
    const int n = n0 + r8 + i * 8, k = k0 + c;
    if (n < N && k < K) dst[(size_t)n * K + k] = f2bf(ts[c][r8 + i * 8]);
  }
}

// ---------------------------------------------------------------------------
// K1: embedding gather + mean pool (bf16 table).  wave-per-(b,s) row.
// ---------------------------------------------------------------------------
__global__ __launch_bounds__(256) void k_embed(const int* __restrict__ uc,
                                               const u16* __restrict__ emb,
                                               u32* __restrict__ click) {
  const int wave = threadIdx.x >> 6, lane = threadIdx.x & 63;
  const int bs = blockIdx.x * 4 + wave;
  __shared__ int rows[4][LL];
  if (lane < LL) rows[wave][lane] = uc[(size_t)bs * LL + lane];
  __syncthreads();
  float ax[4] = {0.f, 0.f, 0.f, 0.f}, ay[4] = {0.f, 0.f, 0.f, 0.f};
  for (int l = 0; l < LL; ++l) {
    const u32* row = (const u32*)(emb + (size_t)rows[wave][l] * DD);
    const u32 a = row[lane], b = row[lane + 64], c = row[lane + 128];
    ax[0] += lo2f(a); ay[0] += hi2f(a);
    ax[1] += lo2f(b); ay[1] += hi2f(b);
    ax[2] += lo2f(c); ay[2] += hi2f(c);
    if (lane < 8) { const u32 d = row[lane + 192]; ax[3] += lo2f(d); ay[3] += hi2f(d); }
  }
  const float s = 1.0f / (float)LL;
  u32* orow = click + (size_t)bs * 200;
  orow[lane]       = packf2(ax[0] * s, ay[0] * s);
  orow[lane + 64]  = packf2(ax[1] * s, ay[1] * s);
  orow[lane + 128] = packf2(ax[2] * s, ay[2] * s);
  if (lane < 8) orow[lane + 192] = packf2(ax[3] * s, ay[3] * s);
}

// ---------------------------------------------------------------------------
// K2: QKV projection, bf16 MFMA.  grid (200, 15), one mat per block
// (mat = y/5, ntile = y%5) — A refetches served by cache hierarchy.
// HEAD-MAJOR output: O[h][m][dh], h = col/20, dh = col%20 (attn locality).
// ---------------------------------------------------------------------------
__global__ __launch_bounds__(256) void k_qkv_mfma(const u16* __restrict__ A,
    const u16* __restrict__ Wt, u16* __restrict__ qo, u16* __restrict__ ko_,
    u16* __restrict__ vo) {
  __shared__ u16 As[256][40];
  __shared__ u16 Bs[80][40];
  const int t = threadIdx.x;
  const int wave = t >> 6, lane = t & 63;
  const int q = lane >> 4, l16 = lane & 15;
  const int m0 = blockIdx.x * 256;
  const int mat = blockIdx.y / 5, ntile = blockIdx.y % 5;
  const int nb = ntile * 80;
  const u16* Bt = Wt + (size_t)(mat * 400 + nb) * 400;
  u16* O = (mat == 0) ? qo : ((mat == 1) ? ko_ : vo);
  const int mw = wave * 64;

  v4f acc[4][5];
#pragma unroll
  for (int i = 0; i < 4; ++i)
#pragma unroll
    for (int j = 0; j < 5; ++j) acc[i][j] = (v4f){0.f, 0.f, 0.f, 0.f};

  for (int kt = 0; kt < 13; ++kt) {
    const int k0 = kt * 32;
#pragma unroll
    for (int i = 0; i < 4; ++i) {
      const int id = i * 256 + t;
      const int r = id >> 2, ko = (id & 3) * 8;
      uint4 val = make_uint4(0u, 0u, 0u, 0u);
      if (k0 + ko < 400) val = *(const uint4*)&A[(size_t)(m0 + r) * 400 + k0 + ko];
      *(uint4*)&As[r][ko] = val;
    }
#pragma unroll
    for (int i = 0; i < 2; ++i) {
      const int id = i * 256 + t;
      if (id < 320) {
        const int n = id >> 2, ko = (id & 3) * 8;
        uint4 val = make_uint4(0u, 0u, 0u, 0u);
        if (k0 + ko < 400) val = *(const uint4*)&Bt[(size_t)n * 400 + k0 + ko];
        *(uint4*)&Bs[n][ko] = val;
      }
    }
    __syncthreads();
    v8s a[4], b[5];
#pragma unroll
    for (int ms = 0; ms < 4; ++ms) a[ms] = *(const v8s*)&As[mw + ms * 16 + l16][q * 8];
#pragma unroll
    for (int ns = 0; ns < 5; ++ns) b[ns] = *(const v8s*)&Bs[ns * 16 + l16][q * 8];
#pragma unroll
    for (int ms = 0; ms < 4; ++ms)
#pragma unroll
      for (int ns = 0; ns < 5; ++ns)
        acc[ms][ns] = __builtin_amdgcn_mfma_f32_16x16x32_bf16(a[ms], b[ns], acc[ms][ns], 0, 0, 0);
    __syncthreads();
  }
  // epilogue: head-major store.  D layout col = l16, row = q*4 + reg
#pragma unroll
  for (int ms = 0; ms < 4; ++ms)
#pragma unroll
    for (int ns = 0; ns < 5; ++ns) {
      const v4f c = acc[ms][ns];
      const int col = nb + ns * 16 + l16;
      const int head = col / 20, dh = col % 20;
      u16* Oh = O + (size_t)head * SLAB + dh;
#pragma unroll
      for (int reg = 0; reg < 4; ++reg) {
        const int m = m0 + mw + ms * 16 + q * 4 + reg;
        Oh[(size_t)m * 20] = f2bf(c[reg]);
      }
    }
}

// ---------------------------------------------------------------------------
// K3: MFMA attention, head-major q/k/v input.  One block per (b,h), 4 waves.
// ctx written [bs][400].
// ---------------------------------------------------------------------------
__global__ __launch_bounds__(256) void k_attn_mfma(const u16* __restrict__ qg,
    const u16* __restrict__ kg, const u16* __restrict__ vg,
    const int* __restrict__ seq, u16* __restrict__ ctxg) {
  __shared__ u16 Qs[112][40];
  __shared__ u16 Ks[112][40];
  __shared__ u16 Vs[112][40];
  __shared__ u16 Vt[32][136];
  __shared__ u16 Ss[112][136];
  const int b = blockIdx.x / HH, h = blockIdx.x % HH;
  const int t = threadIdx.x;
  const int wave = t >> 6, lane = t & 63;
  const int quad = lane >> 4, l16 = lane & 15;
  const int len = seq[b];
  const u16* qb = qg + (size_t)h * SLAB + (size_t)b * SS * DHH;
  const u16* kb = kg + (size_t)h * SLAB + (size_t)b * SS * DHH;
  const u16* vb = vg + (size_t)h * SLAB + (size_t)b * SS * DHH;
  for (int id = t; id < 896; id += 256) {
    const int r = id >> 3, ch = id & 7;
    uint2 vq = make_uint2(0u, 0u), vk = vq, vv = vq;
    if (r < 100 && ch < 5) {
      vq = *(const uint2*)(qb + r * DHH + ch * 4);
      vk = *(const uint2*)(kb + r * DHH + ch * 4);
      vv = *(const uint2*)(vb + r * DHH + ch * 4);
    }
    *(uint2*)&Qs[r][ch * 4] = vq;
    *(uint2*)&Ks[r][ch * 4] = vk;
    *(uint2*)&Vs[r][ch * 4] = vv;
  }
  for (int id = t; id < 816; id += 256) ((u32*)&Vt[20][0])[id] = 0u;
  for (int id = t; id < 360; id += 256) {
    const int r = id / 18, c = id % 18;
    *(u32*)&Vt[r][100 + c * 2] = 0u;
  }
  for (int id = t; id < 896; id += 256) {
    const int r = id >> 3, c = id & 7;
    *(u32*)&Ss[r][112 + c * 2] = 0u;
  }
  __syncthreads();
  for (int id = t; id < 2000; id += 256) {
    const int d = id / 100, key = id % 100;
    Vt[d][key] = Vs[key][d];
  }
  const float sc = 0.2236067977499790f;  // 1/sqrt(20)
  for (int mi = 0; mi < 2; ++mi) {
    const int mt = wave + mi * 4;
    if (mt >= 7) break;
    const v8s a = *(const v8s*)&Qs[mt * 16 + l16][quad * 8];
    v4f acc[7];
#pragma unroll
    for (int nt = 0; nt < 7; ++nt) {
      const v8s bk = *(const v8s*)&Ks[nt * 16 + l16][quad * 8];
      acc[nt] = __builtin_amdgcn_mfma_f32_16x16x32_bf16(a, bk, (v4f){0.f,0.f,0.f,0.f}, 0, 0, 0);
    }
#pragma unroll
    for (int reg = 0; reg < 4; ++reg) {
      float v[7];
      float mx = -3.0e38f;
#pragma unroll
      for (int nt = 0; nt < 7; ++nt) {
        const int col = nt * 16 + l16;
        v[nt] = acc[nt][reg] * sc + ((col < len) ? 1.0f : -1e9f);
        mx = fmaxf(mx, v[nt]);
      }
#pragma unroll
      for (int o = 1; o < 16; o <<= 1) mx = fmaxf(mx, __shfl_xor(mx, o));
      float sum = 0.f;
#pragma unroll
      for (int nt = 0; nt < 7; ++nt) { v[nt] = __expf(v[nt] - mx); sum += v[nt]; }
#pragma unroll
      for (int o = 1; o < 16; o <<= 1) sum += __shfl_xor(sum, o);
      const float inv = 1.0f / sum;
      const int row = mt * 16 + quad * 4 + reg;
#pragma unroll
      for (int nt = 0; nt < 7; ++nt) Ss[row][nt * 16 + l16] = f2bf(v[nt] * inv);
    }
  }
  __syncthreads();
  u16* cb = ctxg + (size_t)b * SS * DD + h * DHH;
  for (int mi = 0; mi < 2; ++mi) {
    const int mt = wave + mi * 4;
    if (mt >= 7) break;
    v4f o0 = (v4f){0.f,0.f,0.f,0.f}, o1 = o0;
#pragma unroll
    for (int kc = 0; kc < 4; ++kc) {
      const v8s a  = *(const v8s*)&Ss[mt * 16 + l16][kc * 32 + quad * 8];
      const v8s b0 = *(const v8s*)&Vt[l16][kc * 32 + quad * 8];
      const v8s b1 = *(const v8s*)&Vt[16 + l16][kc * 32 + quad * 8];
      o0 = __builtin_amdgcn_mfma_f32_16x16x32_bf16(a, b0, o0, 0, 0, 0);
      o1 = __builtin_amdgcn_mfma_f32_16x16x32_bf16(a, b1, o1, 0, 0, 0);
    }
#pragma unroll
    for (int reg = 0; reg < 4; ++reg) {
      const int q = mt * 16 + quad * 4 + reg;
      if (q < 100) {
        cb[(size_t)q * DD + l16] = f2bf(o0[reg]);
        if (l16 < 4) cb[(size_t)q * DD + 16 + l16] = f2bf(o1[reg]);
      }
    }
  }
}

// ---------------------------------------------------------------------------
// K4: alpha = tanh(ctx @ fc1_w + f1b) · f2w, fused.  bf16 MFMA + in-register
// row reduce + atomicAdd (2 blocks/row contribute).  e never materialized.
// ---------------------------------------------------------------------------
__global__ __launch_bounds__(256) void k_fc1_alpha(const u16* __restrict__ A,
    const u16* __restrict__ Bt, const float* __restrict__ f1b,
    const float* __restrict__ f2w, float* __restrict__ alpha) {
  __shared__ u16 As[128][40];
  __shared__ u16 Bs[64][40];
  const int t = threadIdx.x;
  const int wave = t >> 6, lane = t & 63;
  const int quad = lane >> 4, l16 = lane & 15;
  const int m0 = blockIdx.x * 128;
  const int nb = blockIdx.y * 64;
  const int mw = wave * 32;
  v4f acc[2][4];
#pragma unroll
  for (int i = 0; i < 2; ++i)
#pragma unroll
    for (int j = 0; j < 4; ++j) acc[i][j] = (v4f){0.f, 0.f, 0.f, 0.f};

  for (int kt = 0; kt < 13; ++kt) {
    const int k0 = kt * 32;
#pragma unroll
    for (int i = 0; i < 2; ++i) {
      const int id = i * 256 + t;
      const int r = id >> 2, ko = (id & 3) * 8;
      uint4 val = make_uint4(0u, 0u, 0u, 0u);
      if (k0 + ko < 400) val = *(const uint4*)&A[(size_t)(m0 + r) * 400 + k0 + ko];
      *(uint4*)&As[r][ko] = val;
    }
    {
      const int r = t >> 2, ko = (t & 3) * 8;
      uint4 val = make_uint4(0u, 0u, 0u, 0u);
      if (k0 + ko < 400) val = *(const uint4*)&Bt[(size_t)(nb + r) * 400 + k0 + ko];
      *(uint4*)&Bs[r][ko] = val;
    }
    __syncthreads();
    v8s a[2], b[4];
#pragma unroll
    for (int ms = 0; ms < 2; ++ms) a[ms] = *(const v8s*)&As[mw + ms * 16 + l16][quad * 8];
#pragma unroll
    for (int ns = 0; ns < 4; ++ns) b[ns] = *(const v8s*)&Bs[ns * 16 + l16][quad * 8];
#pragma unroll
    for (int ms = 0; ms < 2; ++ms)
#pragma unroll
      for (int ns = 0; ns < 4; ++ns)
        acc[ms][ns] = __builtin_amdgcn_mfma_f32_16x16x32_bf16(a[ms], b[ns], acc[ms][ns], 0, 0, 0);
    __syncthreads();
  }
  // epilogue: per-row  p = sum_col tanh(acc + f1b[col]) * f2w[col]
  float fwv[4], fbv[4];
#pragma unroll
  for (int ns = 0; ns < 4; ++ns) {
    fwv[ns] = f2w[nb + ns * 16 + l16];
    fbv[ns] = f1b[nb + ns * 16 + l16];
  }
#pragma unroll
  for (int ms = 0; ms < 2; ++ms)
#pragma unroll
    for (int reg = 0; reg < 4; ++reg) {
      float p = 0.f;
#pragma unroll
      for (int ns = 0; ns < 4; ++ns)
        p += tanhf(acc[ms][ns][reg] + fbv[ns]) * fwv[ns];
#pragma unroll
      for (int o = 1; o < 16; o <<= 1) p += __shfl_xor(p, o);
      if (l16 == 0)
        atomicAdd(&alpha[m0 + mw + ms * 16 + quad * 4 + reg], p);
    }
}

// ---------------------------------------------------------------------------
// K5: additive attention pooling from alpha.  One block per batch row.
// ---------------------------------------------------------------------------
__global__ __launch_bounds__(256) void k_pool(const float* __restrict__ alpha,
    const float* __restrict__ f2b, const int* __restrict__ seq,
    const u16* __restrict__ ctxg, float* __restrict__ out) {
  const int b = blockIdx.x;
  const int t = threadIdx.x, w = t >> 6, lane = t & 63;
  __shared__ float wts[SS];
  const int len = seq[b];
  const float bias = f2b[0];
  if (t < SS) wts[t] = alpha[b * SS + t] + bias + ((t < len) ? 1.0f : -1e9f);
  __syncthreads();
  if (w == 0) {
    const float v0 = wts[lane];
    const float v1 = (lane + 64 < SS) ? wts[lane + 64] : -3.0e38f;
    float mx = fmaxf(v0, v1);
#pragma unroll
    for (int o = 32; o > 0; o >>= 1) mx = fmaxf(mx, __shfl_xor(mx, o));
    const float e0 = __expf(v0 - mx);
    const float e1 = (lane + 64 < SS) ? __expf(v1 - mx) : 0.f;
    float sm = e0 + e1;
#pragma unroll
    for (int o = 32; o > 0; o >>= 1) sm += __shfl_xor(sm, o);
    const float inv = 1.0f / sm;
    wts[lane] = e0 * inv;
    if (lane + 64 < SS) wts[lane + 64] = e1 * inv;
  }
  __syncthreads();
  for (int d = t; d < DD; d += 256) {
    float acc = 0.f;
    const u16* cb = ctxg + (size_t)b * SS * DD + d;
    for (int s = 0; s < SS; ++s) acc += wts[s] * bf2f(cb[(size_t)s * DD]);
    out[(size_t)b * DD + d] = acc;
  }
}

// ---------------------------------------------------------------------------
extern "C" void kernel_launch(void* const* d_in, const int* in_sizes, int n_in,
                              void* d_out, int out_size, void* d_ws, size_t ws_size,
                              hipStream_t stream) {
  const int*   uc  = (const int*)d_in[0];
  const int*   seq = (const int*)d_in[1];
  const float* emb = (const float*)d_in[2];
  const float* wq  = (const float*)d_in[3];
  const float* wk  = (const float*)d_in[4];
  const float* wv  = (const float*)d_in[5];
  const float* f1w = (const float*)d_in[6];
  const float* f1b = (const float*)d_in[7];
  const float* f2w = (const float*)d_in[8];
  const float* f2b = (const float*)d_in[9];
  float* out = (float*)d_out;

  u16* emb16   = (u16*)d_ws;
  u16* wt      = emb16 + 20000000ull;
  u16* wtf     = wt + 480000ull;
  u16* click16 = wtf + 51200ull;               // also ctx16 ([bs][400])
  u16* q16     = click16 + 20480000ull;        // head-major [20][51200][20]
  u16* k16     = q16 + 20480000ull;
  u16* v16     = k16 + 20480000ull;
  float* alpha = (float*)(v16 + 20480000ull);  // [51200] f32
  float* sink  = alpha + 51200ull;

  k_cvt<<<(5000000 + 255) / 256, 256, 0, stream>>>(emb, emb16, 5000000);
  k_warm<<<2560, 256, 0, stream>>>((const uint4*)emb16, 2500000, alpha, 51200, sink);
  k_trans_all<<<dim3(13, 13, 4), 256, 0, stream>>>(wq, wk, wv, f1w, wt, wtf);
  k_embed<<<12800, 256, 0, stream>>>(uc, emb16, (u32*)click16);
  k_qkv_mfma<<<dim3(200, 15), 256, 0, stream>>>(click16, wt, q16, k16, v16);
  k_attn_mfma<<<BB * HH, 256, 0, stream>>>(q16, k16, v16, seq, click16);
  k_fc1_alpha<<<dim3(400, 2), 256, 0, stream>>>(click16, wtf, f1b, f2w, alpha);
  k_pool<<<BB, 256, 0, stream>>>(alpha, f2b, seq, click16, out);
}